// Round 1
// baseline (182.777 us; speedup 1.0000x reference)
//
#include <hip/hip_runtime.h>
#include <hip/hip_bf16.h>
#include <stdint.h>

#define BN_EPS 1e-3f

typedef __bf16 bf16x8 __attribute__((ext_vector_type(8)));
typedef float  f32x16 __attribute__((ext_vector_type(16)));

// Problem dims: B=256, F=64, Df=H=D=256, E=8. Tokens = B*F = 16384, tile BM=64 (one batch row).
// ws layout:
//   [0, 3145728)            packed weights bf16: mat m = L*8+e (L=0:W1,1:W2,2:Wo),
//                           per (m, nb=8, ks=16): 64 lanes x 8 bf16 (16B/lane)
//   [3145728, +32768)       fold: s1[2048], c1[2048], s2[2048], c2[2048]  (f32)
//   [3178496, +2048)        routing weights w[f=64][e=8] f32
static constexpr size_t WS_FOLD_OFF = 24ull * 131072ull;       // 3,145,728
static constexpr size_t WS_WRT_OFF  = WS_FOLD_OFF + 32768ull;  // 3,178,496

// ---------------- BN fold: s = g*rsqrt(v+eps), c = (b-m)*s + beta ----------------
__global__ __launch_bounds__(256) void fold_kernel(
    const float* __restrict__ b1, const float* __restrict__ g1, const float* __restrict__ be1,
    const float* __restrict__ m1, const float* __restrict__ v1,
    const float* __restrict__ b2, const float* __restrict__ g2, const float* __restrict__ be2,
    const float* __restrict__ m2, const float* __restrict__ v2,
    float* __restrict__ fold) {
  int i = blockIdx.x * 256 + threadIdx.x;   // grid 8 -> 2048
  if (i < 2048) {
    float s1 = g1[i] * rsqrtf(v1[i] + BN_EPS);
    fold[i]        = s1;
    fold[2048 + i] = (b1[i] - m1[i]) * s1 + be1[i];
    float s2 = g2[i] * rsqrtf(v2[i] + BN_EPS);
    fold[4096 + i] = s2;
    fold[6144 + i] = (b2[i] - m2[i]) * s2 + be2[i];
  }
}

// ---------------- Weight pack: fp32 [E][K=256][N=256] -> bf16 MFMA-frag order ----------------
// lane l of block (m, nb, ks) holds W[k = ks*16 + (l>>5)*8 + i][n = nb*32 + (l&31)], i=0..7
__global__ __launch_bounds__(256) void pack_kernel(
    const float* __restrict__ W1, const float* __restrict__ W2, const float* __restrict__ Wo,
    __bf16* __restrict__ pk) {
  __shared__ float sl[16 * 256];
  int bid = blockIdx.x;             // 384 = 24 mats * 16 ks
  int m = bid >> 4, ks = bid & 15;
  int L = m >> 3, e = m & 7;
  const float* Ws = (L == 0 ? W1 : (L == 1 ? W2 : Wo)) + (size_t)e * 65536 + (size_t)ks * 16 * 256;
  int t = threadIdx.x;
#pragma unroll
  for (int it = 0; it < 4; ++it) {
    int el4 = it * 256 + t;
    float4 v = *reinterpret_cast<const float4*>(Ws + (size_t)el4 * 4);
    *reinterpret_cast<float4*>(&sl[el4 * 4]) = v;
  }
  __syncthreads();
#pragma unroll
  for (int it = 0; it < 2; ++it) {
    int task = it * 256 + t;        // 512 tasks: nb(8) x lane(64)
    int nb = task >> 6, l = task & 63;
    int colb = nb * 32 + (l & 31);
    int krow = (l >> 5) * 8;
    union { __bf16 h[8]; int4 v; } u;
#pragma unroll
    for (int i = 0; i < 8; ++i) u.h[i] = (__bf16)sl[(krow + i) * 256 + colb];
    size_t off = ((size_t)(m * 8 + nb) * 16 + ks) * 512 + (size_t)l * 8;  // elements
    *reinterpret_cast<int4*>(pk + off) = u.v;
  }
}

// ---------------- Routing: feat = mean_b x -> feat@Wr+br -> softmax ----------------
__global__ __launch_bounds__(256) void route_kernel(
    const float* __restrict__ x, const float* __restrict__ Wr, const float* __restrict__ br,
    float* __restrict__ wrt) {
  __shared__ float feat[256];
  __shared__ float lg[8];
  int f = blockIdx.x, t = threadIdx.x;
  float acc = 0.f;
  const float* xp = x + (size_t)f * 256 + t;
  for (int b = 0; b < 256; ++b) acc += xp[(size_t)b * 16384];
  feat[t] = acc * (1.0f / 256.0f);
  __syncthreads();
  if (t < 8) {
    float a = br[t];
    for (int d = 0; d < 256; ++d) a += feat[d] * Wr[d * 8 + t];
    lg[t] = a;
  }
  __syncthreads();
  if (t == 0) {
    float mx = lg[0];
#pragma unroll
    for (int e = 1; e < 8; ++e) mx = fmaxf(mx, lg[e]);
    float ex[8]; float s = 0.f;
#pragma unroll
    for (int e = 0; e < 8; ++e) { ex[e] = expf(lg[e] - mx); s += ex[e]; }
    float inv = 1.0f / s;
#pragma unroll
    for (int e = 0; e < 8; ++e) wrt[f * 8 + e] = ex[e] * inv;
  }
}

// ---------------- Main fused MoE ----------------
// grid 256 (one WG per batch row b, 64 tokens), 256 threads = 4 waves.
// Wave w owns output cols [w*64, w*64+64) (two 32-wide n-tiles); all 64 rows.
// LDS: xb[64][256] bf16 (persistent), hb[64][256] bf16 (reused per layer), both XOR-swizzled.
__global__ __launch_bounds__(256, 1) void moe_kernel(
    const float* __restrict__ x, const __bf16* __restrict__ pk,
    const float* __restrict__ fold, const float* __restrict__ wrt,
    const float* __restrict__ bo, float* __restrict__ out) {
  __shared__ char xbuf[32768];
  __shared__ char hbuf[32768];
  const int tid = threadIdx.x;
  const int l = tid & 63, w = tid >> 6;
  const int b = blockIdx.x;

  // ---- stage x tile -> bf16 LDS (swizzled) ----
  {
    const float* xg = x + (size_t)b * 16384;
#pragma unroll
    for (int it = 0; it < 16; ++it) {
      int el = (it * 256 + tid) * 4;
      int row = el >> 8, col = el & 255;
      float4 v = *reinterpret_cast<const float4*>(xg + el);
      union { __bf16 h[4]; short4 s; } u;
      u.h[0] = (__bf16)v.x; u.h[1] = (__bf16)v.y; u.h[2] = (__bf16)v.z; u.h[3] = (__bf16)v.w;
      int byte = (col * 2) ^ ((row & 7) << 4);
      *reinterpret_cast<short4*>(xbuf + row * 512 + byte) = u.s;
    }
  }

  f32x16 outacc[2][2];
#pragma unroll
  for (int mt = 0; mt < 2; ++mt)
#pragma unroll
    for (int nt = 0; nt < 2; ++nt)
#pragma unroll
      for (int r = 0; r < 16; ++r) outacc[mt][nt][r] = 0.f;

  const int nb0 = 2 * w;
  const int arow = l & 31;
  const int abyte_lane = (l >> 5) * 16;
  const int aswz = (l & 7) << 4;

  __syncthreads();

  for (int e = 0; e < 8; ++e) {
#pragma unroll
    for (int L = 0; L < 3; ++L) {
      const char* src = (L == 0) ? xbuf : hbuf;
      f32x16 acc[2][2];
#pragma unroll
      for (int mt = 0; mt < 2; ++mt)
#pragma unroll
        for (int nt = 0; nt < 2; ++nt)
#pragma unroll
          for (int r = 0; r < 16; ++r) acc[mt][nt][r] = 0.f;

      const __bf16* pb = pk + (size_t)((L * 8 + e) * 8 + nb0) * 8192;
#pragma unroll
      for (int ks = 0; ks < 16; ++ks) {
        int abyte = (ks * 32 + abyte_lane) ^ aswz;
        bf16x8 a0 = *reinterpret_cast<const bf16x8*>(src + (0 * 32 + arow) * 512 + abyte);
        bf16x8 a1 = *reinterpret_cast<const bf16x8*>(src + (1 * 32 + arow) * 512 + abyte);
        bf16x8 b0 = *reinterpret_cast<const bf16x8*>(pb + (size_t)ks * 512 + (size_t)l * 8);
        bf16x8 b1 = *reinterpret_cast<const bf16x8*>(pb + 8192 + (size_t)ks * 512 + (size_t)l * 8);
        acc[0][0] = __builtin_amdgcn_mfma_f32_32x32x16_bf16(a0, b0, acc[0][0], 0, 0, 0);
        acc[0][1] = __builtin_amdgcn_mfma_f32_32x32x16_bf16(a0, b1, acc[0][1], 0, 0, 0);
        acc[1][0] = __builtin_amdgcn_mfma_f32_32x32x16_bf16(a1, b0, acc[1][0], 0, 0, 0);
        acc[1][1] = __builtin_amdgcn_mfma_f32_32x32x16_bf16(a1, b1, acc[1][1], 0, 0, 0);
      }
      __syncthreads();  // all waves done READING src (hb reuse safety)

      if (L < 2) {
        const float* sA = fold + L * 4096;
        const float* cA = fold + L * 4096 + 2048;
#pragma unroll
        for (int nt = 0; nt < 2; ++nt) {
          int col = (nb0 + nt) * 32 + (l & 31);
          float s = sA[e * 256 + col], c = cA[e * 256 + col];
#pragma unroll
          for (int mt = 0; mt < 2; ++mt) {
#pragma unroll
            for (int r = 0; r < 16; ++r) {
              int row = mt * 32 + 4 * (l >> 5) + (r & 3) + 8 * (r >> 2);
              float v = fmaxf(acc[mt][nt][r] * s + c, 0.f);
              int byte = (col * 2) ^ ((row & 7) << 4);
              *reinterpret_cast<__bf16*>(hbuf + row * 512 + byte) = (__bf16)v;
            }
          }
        }
      } else {
#pragma unroll
        for (int nt = 0; nt < 2; ++nt) {
          int col = (nb0 + nt) * 32 + (l & 31);
          float bv = bo[e * 256 + col];
#pragma unroll
          for (int mt = 0; mt < 2; ++mt) {
#pragma unroll
            for (int r = 0; r < 16; ++r) {
              int row = mt * 32 + 4 * (l >> 5) + (r & 3) + 8 * (r >> 2);
              float wv = wrt[row * 8 + e];
              outacc[mt][nt][r] += wv * (acc[mt][nt][r] + bv);
            }
          }
        }
      }
      __syncthreads();  // writes to hb visible before next layer reads
    }
  }

  // ---- store out tile ----
  float* og = out + (size_t)b * 16384;
#pragma unroll
  for (int nt = 0; nt < 2; ++nt) {
    int col = (nb0 + nt) * 32 + (l & 31);
#pragma unroll
    for (int mt = 0; mt < 2; ++mt) {
#pragma unroll
      for (int r = 0; r < 16; ++r) {
        int row = mt * 32 + 4 * (l >> 5) + (r & 3) + 8 * (r >> 2);
        og[row * 256 + col] = outacc[mt][nt][r];
      }
    }
  }
}

extern "C" void kernel_launch(void* const* d_in, const int* in_sizes, int n_in,
                              void* d_out, int out_size, void* d_ws, size_t ws_size,
                              hipStream_t stream) {
  const float* x   = (const float*)d_in[0];
  const float* Wr  = (const float*)d_in[1];
  const float* br  = (const float*)d_in[2];
  const float* W1  = (const float*)d_in[3];
  const float* b1  = (const float*)d_in[4];
  const float* g1  = (const float*)d_in[5];
  const float* be1 = (const float*)d_in[6];
  const float* m1  = (const float*)d_in[7];
  const float* v1  = (const float*)d_in[8];
  const float* W2  = (const float*)d_in[9];
  const float* b2  = (const float*)d_in[10];
  const float* g2  = (const float*)d_in[11];
  const float* be2 = (const float*)d_in[12];
  const float* m2  = (const float*)d_in[13];
  const float* v2  = (const float*)d_in[14];
  const float* Wo  = (const float*)d_in[15];
  const float* bo  = (const float*)d_in[16];
  float* out = (float*)d_out;

  __bf16* pk  = (__bf16*)d_ws;
  float* fold = (float*)((char*)d_ws + WS_FOLD_OFF);
  float* wrt  = (float*)((char*)d_ws + WS_WRT_OFF);

  hipLaunchKernelGGL(fold_kernel, dim3(8), dim3(256), 0, stream,
                     b1, g1, be1, m1, v1, b2, g2, be2, m2, v2, fold);
  hipLaunchKernelGGL(pack_kernel, dim3(384), dim3(256), 0, stream, W1, W2, Wo, pk);
  hipLaunchKernelGGL(route_kernel, dim3(64), dim3(256), 0, stream, x, Wr, br, wrt);
  hipLaunchKernelGGL(moe_kernel, dim3(256), dim3(256), 0, stream, x, pk, fold, wrt, bo, out);
}

// Round 2
// 105.888 us; speedup vs baseline: 1.7261x; 1.7261x over previous
//
#include <hip/hip_runtime.h>
#include <hip/hip_bf16.h>
#include <stdint.h>

#define BN_EPS 1e-3f

typedef __bf16 bf16x8 __attribute__((ext_vector_type(8)));
typedef float  f32x16 __attribute__((ext_vector_type(16)));

// Dims: B=256, F=64, Df=H=D=256, E=8. WG = one batch row b -> 64 tokens.
// ws layout:
//   [0, 3145728)   packed weights bf16, mat m = L*8+e, block (m, nb, ks): 64 lanes x 8 bf16
//   [+32768)       fold: s1[2048], c1[2048], s2[2048], c2[2048] (f32)
//   [+2048)        routing weights wrt[f=64][e=8] f32
//   [+65536)       wb[f=64][col=256] f32 = sum_e wrt*bo
static constexpr size_t WS_FOLD_OFF = 24ull * 131072ull;
static constexpr size_t WS_WRT_OFF  = WS_FOLD_OFF + 32768ull;
static constexpr size_t WS_WB_OFF   = WS_WRT_OFF + 2048ull;

// ---------------- BN fold ----------------
__global__ __launch_bounds__(256) void fold_kernel(
    const float* __restrict__ b1, const float* __restrict__ g1, const float* __restrict__ be1,
    const float* __restrict__ m1, const float* __restrict__ v1,
    const float* __restrict__ b2, const float* __restrict__ g2, const float* __restrict__ be2,
    const float* __restrict__ m2, const float* __restrict__ v2,
    float* __restrict__ fold) {
  int i = blockIdx.x * 256 + threadIdx.x;
  if (i < 2048) {
    float s1 = g1[i] * rsqrtf(v1[i] + BN_EPS);
    fold[i]        = s1;
    fold[2048 + i] = (b1[i] - m1[i]) * s1 + be1[i];
    float s2 = g2[i] * rsqrtf(v2[i] + BN_EPS);
    fold[4096 + i] = s2;
    fold[6144 + i] = (b2[i] - m2[i]) * s2 + be2[i];
  }
}

// ---------------- Weight pack: fp32 [E][K][N] -> bf16 MFMA-frag order ----------------
// lane l of block (m, nb, ks) holds W[k = ks*16 + (l>>5)*8 + i][n = nb*32 + (l&31)]
__global__ __launch_bounds__(256) void pack_kernel(
    const float* __restrict__ W1, const float* __restrict__ W2, const float* __restrict__ Wo,
    __bf16* __restrict__ pk) {
  __shared__ float sl[16 * 256];
  int bid = blockIdx.x;             // 384 = 24 mats * 16 ks
  int m = bid >> 4, ks = bid & 15;
  int L = m >> 3, e = m & 7;
  const float* Ws = (L == 0 ? W1 : (L == 1 ? W2 : Wo)) + (size_t)e * 65536 + (size_t)ks * 16 * 256;
  int t = threadIdx.x;
#pragma unroll
  for (int it = 0; it < 4; ++it) {
    int el4 = it * 256 + t;
    float4 v = *reinterpret_cast<const float4*>(Ws + (size_t)el4 * 4);
    *reinterpret_cast<float4*>(&sl[el4 * 4]) = v;
  }
  __syncthreads();
#pragma unroll
  for (int it = 0; it < 2; ++it) {
    int task = it * 256 + t;        // nb(8) x lane(64)
    int nb = task >> 6, l = task & 63;
    int colb = nb * 32 + (l & 31);
    int krow = (l >> 5) * 8;
    union { __bf16 h[8]; int4 v; } u;
#pragma unroll
    for (int i = 0; i < 8; ++i) u.h[i] = (__bf16)sl[(krow + i) * 256 + colb];
    size_t off = ((size_t)(m * 8 + nb) * 16 + ks) * 512 + (size_t)l * 8;
    *reinterpret_cast<int4*>(pk + off) = u.v;
  }
}

// ---------------- Routing + wb = wrt @ bo ----------------
__global__ __launch_bounds__(256) void route_kernel(
    const float* __restrict__ x, const float* __restrict__ Wr, const float* __restrict__ br,
    const float* __restrict__ bo, float* __restrict__ wrt, float* __restrict__ wb) {
  __shared__ float feat[256];
  __shared__ float lg[8];
  __shared__ float wsm[8];
  int f = blockIdx.x, t = threadIdx.x;
  float acc = 0.f;
  const float* xp = x + (size_t)f * 256 + t;
  for (int b = 0; b < 256; ++b) acc += xp[(size_t)b * 16384];
  feat[t] = acc * (1.0f / 256.0f);
  __syncthreads();
  if (t < 8) {
    float a = br[t];
    for (int d = 0; d < 256; ++d) a += feat[d] * Wr[d * 8 + t];
    lg[t] = a;
  }
  __syncthreads();
  if (t == 0) {
    float mx = lg[0];
#pragma unroll
    for (int e = 1; e < 8; ++e) mx = fmaxf(mx, lg[e]);
    float ex[8]; float s = 0.f;
#pragma unroll
    for (int e = 0; e < 8; ++e) { ex[e] = expf(lg[e] - mx); s += ex[e]; }
    float inv = 1.0f / s;
#pragma unroll
    for (int e = 0; e < 8; ++e) { float v = ex[e] * inv; wsm[e] = v; wrt[f * 8 + e] = v; }
  }
  __syncthreads();
  float o = 0.f;
#pragma unroll
  for (int e = 0; e < 8; ++e) o += wsm[e] * bo[e * 256 + t];
  wb[f * 256 + t] = o;
}

// ---------------- Main fused MoE ----------------
// grid 256 (one WG per batch row), 512 threads = 8 waves. Wave w owns col-tile nb=w (32 cols).
// LDS fragment-major: buf[fragrow = 2*ks + half][token] of 16B; fragrow f holds k in [8f, 8f+8).
// ds_read_b128 / packed b64 writes are contiguous per half-wave -> conflict-free.
__global__ __launch_bounds__(512, 2) void moe_kernel(
    const float* __restrict__ x, const __bf16* __restrict__ pk,
    const float* __restrict__ fold, const float* __restrict__ wrt,
    const float* __restrict__ wb, float* __restrict__ out) {
  __shared__ char xb[32768];
  __shared__ char h1[32768];
  __shared__ char h2[32768];
  const int tid = threadIdx.x;
  const int l = tid & 63, w = tid >> 6;
  const int l31 = l & 31, hi = l >> 5;
  const int b = blockIdx.x;

  // ---- stage x -> bf16 LDS, fragment-major ----
  {
    const float* xg = x + (size_t)b * 16384;
#pragma unroll
    for (int it = 0; it < 8; ++it) {
      int el4 = it * 512 + tid;          // 4096 float4 tasks
      int token = el4 >> 6;
      int k4 = (el4 & 63) * 4;
      float4 v = *reinterpret_cast<const float4*>(xg + (size_t)el4 * 4);
      union { __bf16 h[4]; short4 s; } u;
      u.h[0] = (__bf16)v.x; u.h[1] = (__bf16)v.y; u.h[2] = (__bf16)v.z; u.h[3] = (__bf16)v.w;
      int addr = (((k4 >> 3) * 64 + token) << 4) + ((k4 & 4) << 1);
      *reinterpret_cast<short4*>(xb + addr) = u.s;
    }
  }

  f32x16 outacc[2];
#pragma unroll
  for (int mt = 0; mt < 2; ++mt)
#pragma unroll
    for (int r = 0; r < 16; ++r) outacc[mt][r] = 0.f;

  __syncthreads();

#define FRAG(buf, fr, tok) (*reinterpret_cast<const bf16x8*>((buf) + ((((fr) * 64) + (tok)) << 4)))

#pragma unroll 1
  for (int e = 0; e < 8; ++e) {
    // ===== L0 (swapped): h1^T_local = mfma(W1frag, xfrag) =====
    {
      f32x16 a0, a1;
#pragma unroll
      for (int r = 0; r < 16; ++r) { a0[r] = 0.f; a1[r] = 0.f; }
      const __bf16* pb = pk + (size_t)((0 * 8 + e) * 8 + w) * 8192;
#pragma unroll
      for (int ks = 0; ks < 16; ++ks) {
        bf16x8 wf = *reinterpret_cast<const bf16x8*>(pb + (size_t)ks * 512 + (size_t)l * 8);
        bf16x8 x0 = FRAG(xb, 2 * ks + hi, l31);
        bf16x8 x1 = FRAG(xb, 2 * ks + hi, 32 + l31);
        a0 = __builtin_amdgcn_mfma_f32_32x32x16_bf16(wf, x0, a0, 0, 0, 0);
        a1 = __builtin_amdgcn_mfma_f32_32x32x16_bf16(wf, x1, a1, 0, 0, 0);
      }
      // epilogue: BN+relu, pack 4 bf16, write h1 (frag-major)
      const float* sA = fold + 0 * 4096 + e * 256 + w * 32 + 4 * hi;
      const float* cA = sA + 2048;
#pragma unroll
      for (int g = 0; g < 4; ++g) {
        float4 s4 = *reinterpret_cast<const float4*>(sA + 8 * g);
        float4 c4 = *reinterpret_cast<const float4*>(cA + 8 * g);
        union { __bf16 h[4]; uint2 u; } p0, p1;
#pragma unroll
        for (int j = 0; j < 4; ++j) {
          float sj = (&s4.x)[j], cj = (&c4.x)[j];
          p0.h[j] = (__bf16)fmaxf(a0[4 * g + j] * sj + cj, 0.f);
          p1.h[j] = (__bf16)fmaxf(a1[4 * g + j] * sj + cj, 0.f);
        }
        int addr = (((w * 4 + g) * 64 + l31) << 4) + hi * 8;
        *reinterpret_cast<uint2*>(h1 + addr) = p0.u;
        *reinterpret_cast<uint2*>(h1 + addr + 512) = p1.u;
      }
    }
    __syncthreads();

    // ===== L1 (swapped): h2 from h1 =====
    {
      f32x16 a0, a1;
#pragma unroll
      for (int r = 0; r < 16; ++r) { a0[r] = 0.f; a1[r] = 0.f; }
      const __bf16* pb = pk + (size_t)((1 * 8 + e) * 8 + w) * 8192;
#pragma unroll
      for (int ks = 0; ks < 16; ++ks) {
        bf16x8 wf = *reinterpret_cast<const bf16x8*>(pb + (size_t)ks * 512 + (size_t)l * 8);
        bf16x8 x0 = FRAG(h1, 2 * ks + hi, l31);
        bf16x8 x1 = FRAG(h1, 2 * ks + hi, 32 + l31);
        a0 = __builtin_amdgcn_mfma_f32_32x32x16_bf16(wf, x0, a0, 0, 0, 0);
        a1 = __builtin_amdgcn_mfma_f32_32x32x16_bf16(wf, x1, a1, 0, 0, 0);
      }
      const float* sA = fold + 1 * 4096 + e * 256 + w * 32 + 4 * hi;
      const float* cA = sA + 2048;
#pragma unroll
      for (int g = 0; g < 4; ++g) {
        float4 s4 = *reinterpret_cast<const float4*>(sA + 8 * g);
        float4 c4 = *reinterpret_cast<const float4*>(cA + 8 * g);
        union { __bf16 h[4]; uint2 u; } p0, p1;
#pragma unroll
        for (int j = 0; j < 4; ++j) {
          float sj = (&s4.x)[j], cj = (&c4.x)[j];
          p0.h[j] = (__bf16)fmaxf(a0[4 * g + j] * sj + cj, 0.f);
          p1.h[j] = (__bf16)fmaxf(a1[4 * g + j] * sj + cj, 0.f);
        }
        int addr = (((w * 4 + g) * 64 + l31) << 4) + hi * 8;
        *reinterpret_cast<uint2*>(h2 + addr) = p0.u;
        *reinterpret_cast<uint2*>(h2 + addr + 512) = p1.u;
      }
    }
    __syncthreads();

    // ===== L2 (normal): y = mfma(h2frag, Wofrag); weighted accumulate =====
    {
      f32x16 a0, a1;
#pragma unroll
      for (int r = 0; r < 16; ++r) { a0[r] = 0.f; a1[r] = 0.f; }
      const __bf16* pb = pk + (size_t)((2 * 8 + e) * 8 + w) * 8192;
#pragma unroll
      for (int ks = 0; ks < 16; ++ks) {
        bf16x8 bfr = *reinterpret_cast<const bf16x8*>(pb + (size_t)ks * 512 + (size_t)l * 8);
        bf16x8 h0 = FRAG(h2, 2 * ks + hi, l31);
        bf16x8 hm = FRAG(h2, 2 * ks + hi, 32 + l31);
        a0 = __builtin_amdgcn_mfma_f32_32x32x16_bf16(h0, bfr, a0, 0, 0, 0);
        a1 = __builtin_amdgcn_mfma_f32_32x32x16_bf16(hm, bfr, a1, 0, 0, 0);
      }
#pragma unroll
      for (int mt = 0; mt < 2; ++mt) {
        const f32x16& am = (mt == 0) ? a0 : a1;
#pragma unroll
        for (int r = 0; r < 16; ++r) {
          int row = mt * 32 + 4 * hi + (r & 3) + 8 * (r >> 2);
          float wv = wrt[row * 8 + e];
          outacc[mt][r] += wv * am[r];
        }
      }
    }
    // no barrier needed here: next L0 writes h1 (last read 2 barriers ago)
  }

  // ---- store out tile (+ precombined bias term) ----
  float* og = out + (size_t)b * 16384;
  const int col = w * 32 + l31;
#pragma unroll
  for (int mt = 0; mt < 2; ++mt) {
#pragma unroll
    for (int r = 0; r < 16; ++r) {
      int row = mt * 32 + 4 * hi + (r & 3) + 8 * (r >> 2);
      og[row * 256 + col] = outacc[mt][r] + wb[row * 256 + col];
    }
  }
#undef FRAG
}

extern "C" void kernel_launch(void* const* d_in, const int* in_sizes, int n_in,
                              void* d_out, int out_size, void* d_ws, size_t ws_size,
                              hipStream_t stream) {
  const float* x   = (const float*)d_in[0];
  const float* Wr  = (const float*)d_in[1];
  const float* br  = (const float*)d_in[2];
  const float* W1  = (const float*)d_in[3];
  const float* b1  = (const float*)d_in[4];
  const float* g1  = (const float*)d_in[5];
  const float* be1 = (const float*)d_in[6];
  const float* m1  = (const float*)d_in[7];
  const float* v1  = (const float*)d_in[8];
  const float* W2  = (const float*)d_in[9];
  const float* b2  = (const float*)d_in[10];
  const float* g2  = (const float*)d_in[11];
  const float* be2 = (const float*)d_in[12];
  const float* m2  = (const float*)d_in[13];
  const float* v2  = (const float*)d_in[14];
  const float* Wo  = (const float*)d_in[15];
  const float* bo  = (const float*)d_in[16];
  float* out = (float*)d_out;

  __bf16* pk  = (__bf16*)d_ws;
  float* fold = (float*)((char*)d_ws + WS_FOLD_OFF);
  float* wrt  = (float*)((char*)d_ws + WS_WRT_OFF);
  float* wb   = (float*)((char*)d_ws + WS_WB_OFF);

  hipLaunchKernelGGL(fold_kernel, dim3(8), dim3(256), 0, stream,
                     b1, g1, be1, m1, v1, b2, g2, be2, m2, v2, fold);
  hipLaunchKernelGGL(pack_kernel, dim3(384), dim3(256), 0, stream, W1, W2, Wo, pk);
  hipLaunchKernelGGL(route_kernel, dim3(64), dim3(256), 0, stream, x, Wr, br, bo, wrt, wb);
  hipLaunchKernelGGL(moe_kernel, dim3(256), dim3(512), 0, stream, x, pk, fold, wrt, wb, out);
}